// Round 9
// baseline (1357.408 us; speedup 1.0000x reference)
//
#include <hip/hip_runtime.h>
#include <hip/hip_bf16.h>
#include <hip/hip_cooperative_groups.h>

namespace cg = cooperative_groups;

#define N_NODES 100000
#define N_EDGES 1600000
#define DIN 165
#define DHID 82
#define DH 128
#define DG 64

typedef _Float16 f16;
typedef f16 f16x8 __attribute__((ext_vector_type(8)));
typedef f16 f16x4 __attribute__((ext_vector_type(4)));
typedef f16 f16x2 __attribute__((ext_vector_type(2)));
typedef float f32x4 __attribute__((ext_vector_type(4)));

#define MFMA16(a, b, c) __builtin_amdgcn_mfma_f32_16x16x32_f16(a, b, c, 0, 0, 0)

// MFMA 16x16x32 fragment layouts (verified, guide m89/m120):
//   A[m][k]: m = lane&15, k = (lane>>4)*8 + j
//   B[k][n]: n = lane&15, k = (lane>>4)*8 + j
//   D[m][n]: n = lane&15, m = (lane>>4)*4 + reg

struct MegaArgs {
    const float* x;
    const int* dst;
    const int* src;
    const float* w1;
    const float* w2;
    const float* wl;
    const float* wr;
    const float* bl;
    f16* Xp;
    f16* H;
    f16* Y;
    f16* t_l;
    f16* x2;
    int* cnt;
    int* rank;
    int* rowptr;
    int* bsum;
    int* boff;
    int* esrc;
};

// fence both sides: release-writeback before the barrier, acquire-invalidate after
// (per-XCD L2s are not coherent; bsum/boff lines are written across XCDs)
#define GSYNC() do { __threadfence(); grid.sync(); __threadfence(); } while (0)

// ============ cooperative mega-kernel: CSR build + dense MFMA chain ============
// grid = 512 blocks x 256 threads = 2 blocks/CU (256-VGPR budget; validation-safe)
__global__ __launch_bounds__(256, 2) void mega_kernel(MegaArgs a) {
    cg::grid_group grid = cg::this_grid();
    int tid = threadIdx.x, blk = blockIdx.x;
    int wave = tid >> 6, lane = tid & 63;
    int q = lane >> 4, l16 = lane & 15;

    // ---- P1: rank atomics (blocks 0..255)  ||  xpad (blocks 256..511) ----
    if (blk < 256) {
        for (int e = blk * 256 + tid; e < N_EDGES; e += 256 * 256)
            a.rank[e] = atomicAdd(&a.cnt[a.dst[e]], 1);
    } else {
        for (int gid = (blk - 256) * 256 + tid; gid < N_NODES * 48; gid += 256 * 256) {
            int node = gid / 48, g = gid % 48;
            int col0 = g * 4;
            f16x4 o;
#pragma unroll
            for (int j = 0; j < 4; j++) {
                int c = col0 + j;
                o[j] = (f16)((c < DIN) ? a.x[(long)node * DIN + c] : 0.f);
            }
            *((f16x4*)(a.Xp + (long)node * 192 + col0)) = o;
        }
    }
    GSYNC();

    // ---- P2: per-block local exclusive scan of cnt (256 nodes/block) ----
    {
        __shared__ int wsum[4];
        int i = blk * 256 + tid;
        int v = (i < N_NODES) ? a.cnt[i] : 0;
        int xv = v;
#pragma unroll
        for (int off = 1; off < 64; off <<= 1) {
            int t = __shfl_up(xv, off);
            if (lane >= off) xv += t;
        }
        if (lane == 63) wsum[wave] = xv;
        __syncthreads();
        if (wave == 0 && lane < 4) {
            int wv = wsum[lane];
#pragma unroll
            for (int off = 1; off < 4; off <<= 1) {
                int t = __shfl_up(wv, off);
                if (lane >= off) wv += t;
            }
            wsum[lane] = wv;
        }
        __syncthreads();
        int off0 = wave ? wsum[wave - 1] : 0;
        if (i <= N_NODES) a.rowptr[i] = off0 + xv - v;  // block-local exclusive
        if (tid == 255) a.bsum[blk] = off0 + xv;        // block total
    }
    GSYNC();

    // ---- P3: block 0 scans the 512 block totals into boff ----
    if (blk == 0) {
        __shared__ int ws2[4];
        __shared__ int carry_s;
        if (tid == 0) carry_s = 0;
        __syncthreads();
        for (int c0 = 0; c0 < 512; c0 += 256) {
            int idx = c0 + tid;
            int v = a.bsum[idx];
            int xv = v;
#pragma unroll
            for (int off = 1; off < 64; off <<= 1) {
                int t = __shfl_up(xv, off);
                if (lane >= off) xv += t;
            }
            if (lane == 63) ws2[wave] = xv;
            __syncthreads();
            if (wave == 0 && lane < 4) {
                int wv = ws2[lane];
#pragma unroll
                for (int off = 1; off < 4; off <<= 1) {
                    int t = __shfl_up(wv, off);
                    if (lane >= off) wv += t;
                }
                ws2[lane] = wv;
            }
            __syncthreads();
            int off0 = (wave ? ws2[wave - 1] : 0) + carry_s;
            a.boff[idx] = off0 + xv - v;
            __syncthreads();
            if (tid == 0) carry_s += ws2[3];
            __syncthreads();
        }
    }
    GSYNC();

    // ---- P3b: fold boff into rowptr (absolute CSR offsets) ----
    {
        int i = blk * 256 + tid;
        if (i <= N_NODES) a.rowptr[i] += a.boff[i >> 8];
    }
    GSYNC();

    // ---- P4: fill scatter prologue (all blocks) + H = relu(Xp@W1) ----
    for (int e = blk * 256 + tid; e < N_EDGES; e += 512 * 256) {
        int d = a.dst[e];
        __builtin_nontemporal_store(a.src[e], &a.esrc[a.rowptr[d] + a.rank[e]]);
    }
    {
        int g = (blk >> 3) & 1;
        int chunk = (blk & 7) + 8 * (blk >> 4);     // 0..255, both g share an XCD
        int nbase = g * 48;
        f16x8 bf[3][6];
#pragma unroll
        for (int nt = 0; nt < 3; nt++) {
            int col = nbase + nt * 16 + l16;
#pragma unroll
            for (int ks = 0; ks < 6; ks++) {
                int kb = ks * 32 + q * 8;
                f16x8 b;
#pragma unroll
                for (int j = 0; j < 8; j++) {
                    int k = kb + j;
                    b[j] = (f16)((k < DIN && col < DHID) ? a.w1[k * DHID + col] : 0.f);
                }
                bf[nt][ks] = b;
            }
        }
        for (int mt = chunk * 4 + wave; mt < 6250; mt += 1024) {
            const f16* xr = a.Xp + (long)(mt * 16 + l16) * 192;
            f32x4 acc[3];
#pragma unroll
            for (int nt = 0; nt < 3; nt++) acc[nt] = (f32x4){0.f, 0.f, 0.f, 0.f};
#pragma unroll
            for (int ks = 0; ks < 6; ks++) {
                f16x8 av = *((const f16x8*)(xr + ks * 32 + q * 8));
#pragma unroll
                for (int nt = 0; nt < 3; nt++) acc[nt] = MFMA16(av, bf[nt][ks], acc[nt]);
            }
#pragma unroll
            for (int nt = 0; nt < 3; nt++) {
                int col = nbase + nt * 16 + l16;
#pragma unroll
                for (int r = 0; r < 4; r++) {
                    int node = mt * 16 + q * 4 + r;
                    a.H[(long)node * 96 + col] = (f16)fmaxf(acc[nt][r], 0.f);
                }
            }
        }
    }
    GSYNC();

    // ---- P5: Y = Xp * sigmoid(2*(H @ W2)) ----
    {
        int g = (blk >> 3) & 3;
        int chunk = (blk & 7) + 8 * (blk >> 5);     // 0..127, 4 g-groups share an XCD
        int nbase = g * 48;
        f16x8 bf[3][3];
#pragma unroll
        for (int nt = 0; nt < 3; nt++) {
            int col = nbase + nt * 16 + l16;
#pragma unroll
            for (int ks = 0; ks < 3; ks++) {
                int kb = ks * 32 + q * 8;
                f16x8 b;
#pragma unroll
                for (int j = 0; j < 8; j++) {
                    int k = kb + j;
                    b[j] = (f16)((k < DHID && col < DIN) ? a.w2[k * DIN + col] : 0.f);
                }
                bf[nt][ks] = b;
            }
        }
        for (int mt = chunk * 4 + wave; mt < 6250; mt += 512) {
            const f16* hr = a.H + (long)(mt * 16 + l16) * 96;
            f32x4 acc[3];
#pragma unroll
            for (int nt = 0; nt < 3; nt++) acc[nt] = (f32x4){0.f, 0.f, 0.f, 0.f};
#pragma unroll
            for (int ks = 0; ks < 3; ks++) {
                f16x8 av = *((const f16x8*)(hr + ks * 32 + q * 8));
#pragma unroll
                for (int nt = 0; nt < 3; nt++) acc[nt] = MFMA16(av, bf[nt][ks], acc[nt]);
            }
#pragma unroll
            for (int nt = 0; nt < 3; nt++) {
                int col = nbase + nt * 16 + l16;
#pragma unroll
                for (int r = 0; r < 4; r++) {
                    int node = mt * 16 + q * 4 + r;
                    float gg = 1.f / (1.f + __expf(-2.f * acc[nt][r]));
                    float xv = (float)a.Xp[(long)node * 192 + col];
                    a.Y[(long)node * 192 + col] = (f16)(xv * gg);
                }
            }
        }
    }
    GSYNC();

    // ---- P6: t_l = Y@WL ; x2pre = Y@WR + bl ----
    {
        int g = (blk >> 3) & 3;                     // 0,1 -> WL ; 2,3 -> WR
        int chunk = (blk & 7) + 8 * (blk >> 5);     // 0..127
        bool isR = (g >= 2);
        const float* W = isR ? a.wr : a.wl;
        int cbase = (g & 1) * 64;
        f16x8 bf[4][6];
        float blv[4];
#pragma unroll
        for (int nt = 0; nt < 4; nt++) {
            int col = cbase + nt * 16 + l16;
            blv[nt] = isR ? a.bl[col] : 0.f;
#pragma unroll
            for (int ks = 0; ks < 6; ks++) {
                int kb = ks * 32 + q * 8;
                f16x8 b;
#pragma unroll
                for (int j = 0; j < 8; j++) {
                    int k = kb + j;
                    b[j] = (f16)((k < DIN) ? W[k * DH + col] : 0.f);
                }
                bf[nt][ks] = b;
            }
        }
        for (int mt = chunk * 4 + wave; mt < 6250; mt += 512) {
            const f16* yrow = a.Y + (long)(mt * 16 + l16) * 192;
            f32x4 acc[4];
#pragma unroll
            for (int nt = 0; nt < 4; nt++) acc[nt] = (f32x4){0.f, 0.f, 0.f, 0.f};
#pragma unroll
            for (int ks = 0; ks < 6; ks++) {
                f16x8 av = *((const f16x8*)(yrow + ks * 32 + q * 8));
#pragma unroll
                for (int nt = 0; nt < 4; nt++) acc[nt] = MFMA16(av, bf[nt][ks], acc[nt]);
            }
#pragma unroll
            for (int nt = 0; nt < 4; nt++) {
                int col = cbase + nt * 16 + l16;
#pragma unroll
                for (int r = 0; r < 4; r++) {
                    int node = mt * 16 + q * 4 + r;
                    if (isR)
                        a.x2[(long)node * DH + col] = (f16)(acc[nt][r] + blv[nt]);
                    else
                        a.t_l[(long)node * DH + col] = (f16)acc[nt][r];
                }
            }
        }
    }
}

// ==================== FALLBACK PATH (R7-proven kernels) ====================
__global__ __launch_bounds__(256) void rank_xpad_kernel(const float* __restrict__ x,
                                                        f16* __restrict__ Xp,
                                                        const int* __restrict__ dst,
                                                        int* __restrict__ cnt,
                                                        int* __restrict__ rank) {
    int gid = blockIdx.x * 256 + threadIdx.x;
    if (gid < N_EDGES) rank[gid] = atomicAdd(&cnt[dst[gid]], 1);
    int node = gid / 48, g = gid % 48;
    int col0 = g * 4;
    f16x4 o;
#pragma unroll
    for (int j = 0; j < 4; j++) {
        int c = col0 + j;
        o[j] = (f16)((c < DIN) ? x[(long)node * DIN + c] : 0.f);
    }
    *((f16x4*)(Xp + (long)node * 192 + col0)) = o;
}

__global__ __launch_bounds__(1024) void scan1_kernel(const int* __restrict__ cnt,
                                                     int* __restrict__ rowptr,
                                                     int* __restrict__ bsum) {
    __shared__ int wsum[16];
    int tid = threadIdx.x, lane = tid & 63, wid = tid >> 6;
    int i = blockIdx.x * 1024 + tid;
    int v = (i < N_NODES) ? cnt[i] : 0;
    int xv = v;
#pragma unroll
    for (int off = 1; off < 64; off <<= 1) {
        int t = __shfl_up(xv, off);
        if (lane >= off) xv += t;
    }
    if (lane == 63) wsum[wid] = xv;
    __syncthreads();
    if (wid == 0 && lane < 16) {
        int wv = wsum[lane];
#pragma unroll
        for (int off = 1; off < 16; off <<= 1) {
            int t = __shfl_up(wv, off);
            if (lane >= off) wv += t;
        }
        wsum[lane] = wv;
    }
    __syncthreads();
    int off0 = wid ? wsum[wid - 1] : 0;
    if (i < N_NODES) rowptr[i] = off0 + xv - v;
    if (tid == 1023) bsum[blockIdx.x] = off0 + xv;
}

__global__ __launch_bounds__(64) void scan2_kernel(const int* __restrict__ bsum,
                                                   int* __restrict__ boff,
                                                   int* __restrict__ rowptr,
                                                   int nblocks) {
    int lane = threadIdx.x;
    int c = 0;
    for (int base = 0; base < nblocks; base += 64) {
        int idx = base + lane;
        int v = (idx < nblocks) ? bsum[idx] : 0;
        int xv = v;
#pragma unroll
        for (int off = 1; off < 64; off <<= 1) {
            int t = __shfl_up(xv, off);
            if (lane >= off) xv += t;
        }
        if (idx < nblocks) boff[idx] = c + xv - v;
        c += __shfl(xv, 63);
    }
    if (lane == 0) rowptr[N_NODES] = c;
}

__global__ __launch_bounds__(1024) void scan3_kernel(int* __restrict__ rowptr,
                                                     const int* __restrict__ boff) {
    int i = blockIdx.x * 1024 + threadIdx.x;
    if (i < N_NODES) rowptr[i] += boff[blockIdx.x];
}

__global__ __launch_bounds__(256) void h_fill_kernel(const f16* __restrict__ Xp,
                                                     const float* __restrict__ w1,
                                                     f16* __restrict__ H,
                                                     const int* __restrict__ src,
                                                     const int* __restrict__ dst,
                                                     const int* __restrict__ rank,
                                                     const int* __restrict__ rowptr,
                                                     int* __restrict__ esrc) {
    int tid = threadIdx.x, wave = tid >> 6, lane = tid & 63;
    {
        int tg = blockIdx.x * 256 + tid;
        for (int e = tg; e < N_EDGES; e += 384 * 256) {
            int d = dst[e];
            __builtin_nontemporal_store(src[e], &esrc[rowptr[d] + rank[e]]);
        }
    }
    int q = lane >> 4, l16 = lane & 15;
    int blk = blockIdx.x;
    int g = (blk >> 3) & 1;
    int chunk = (blk & 7) + 8 * (blk >> 4);
    int nbase = g * 48;
    f16x8 bf[3][6];
#pragma unroll
    for (int nt = 0; nt < 3; nt++) {
        int col = nbase + nt * 16 + l16;
#pragma unroll
        for (int ks = 0; ks < 6; ks++) {
            int kb = ks * 32 + q * 8;
            f16x8 b;
#pragma unroll
            for (int j = 0; j < 8; j++) {
                int k = kb + j;
                b[j] = (f16)((k < DIN && col < DHID) ? w1[k * DHID + col] : 0.f);
            }
            bf[nt][ks] = b;
        }
    }
    for (int mt = chunk * 4 + wave; mt < 6250; mt += 768) {
        const f16* xr = Xp + (long)(mt * 16 + l16) * 192;
        f32x4 acc[3];
#pragma unroll
        for (int nt = 0; nt < 3; nt++) acc[nt] = (f32x4){0.f, 0.f, 0.f, 0.f};
#pragma unroll
        for (int ks = 0; ks < 6; ks++) {
            f16x8 a = *((const f16x8*)(xr + ks * 32 + q * 8));
#pragma unroll
            for (int nt = 0; nt < 3; nt++) acc[nt] = MFMA16(a, bf[nt][ks], acc[nt]);
        }
#pragma unroll
        for (int nt = 0; nt < 3; nt++) {
            int col = nbase + nt * 16 + l16;
#pragma unroll
            for (int r = 0; r < 4; r++) {
                int node = mt * 16 + q * 4 + r;
                H[(long)node * 96 + col] = (f16)fmaxf(acc[nt][r], 0.f);
            }
        }
    }
}

__global__ __launch_bounds__(256) void y_kernel(const f16* __restrict__ Xp,
                                                const f16* __restrict__ H,
                                                const float* __restrict__ w2,
                                                f16* __restrict__ Y) {
    int tid = threadIdx.x, wave = tid >> 6, lane = tid & 63;
    int q = lane >> 4, l16 = lane & 15;
    int blk = blockIdx.x;
    int g = (blk >> 3) & 3;
    int chunk = (blk & 7) + 8 * (blk >> 5);
    int nbase = g * 48;
    f16x8 bf[3][3];
#pragma unroll
    for (int nt = 0; nt < 3; nt++) {
        int col = nbase + nt * 16 + l16;
#pragma unroll
        for (int ks = 0; ks < 3; ks++) {
            int kb = ks * 32 + q * 8;
            f16x8 b;
#pragma unroll
            for (int j = 0; j < 8; j++) {
                int k = kb + j;
                b[j] = (f16)((k < DHID && col < DIN) ? w2[k * DIN + col] : 0.f);
            }
            bf[nt][ks] = b;
        }
    }
    for (int mt = chunk * 4 + wave; mt < 6250; mt += 768) {
        const f16* hr = H + (long)(mt * 16 + l16) * 96;
        f32x4 acc[3];
#pragma unroll
        for (int nt = 0; nt < 3; nt++) acc[nt] = (f32x4){0.f, 0.f, 0.f, 0.f};
#pragma unroll
        for (int ks = 0; ks < 3; ks++) {
            f16x8 a = *((const f16x8*)(hr + ks * 32 + q * 8));
#pragma unroll
            for (int nt = 0; nt < 3; nt++) acc[nt] = MFMA16(a, bf[nt][ks], acc[nt]);
        }
#pragma unroll
        for (int nt = 0; nt < 3; nt++) {
            int col = nbase + nt * 16 + l16;
#pragma unroll
            for (int r = 0; r < 4; r++) {
                int node = mt * 16 + q * 4 + r;
                float gg = 1.f / (1.f + __expf(-2.f * acc[nt][r]));
                float xv = (float)Xp[(long)node * 192 + col];
                Y[(long)node * 192 + col] = (f16)(xv * gg);
            }
        }
    }
}

__global__ __launch_bounds__(256) void sage_lin_kernel(const f16* __restrict__ Y,
                                                       const float* __restrict__ wl,
                                                       const float* __restrict__ wr,
                                                       const float* __restrict__ bl,
                                                       f16* __restrict__ t_l,
                                                       f16* __restrict__ x2) {
    int tid = threadIdx.x, wave = tid >> 6, lane = tid & 63;
    int q = lane >> 4, l16 = lane & 15;
    int blk = blockIdx.x;
    int g = (blk >> 3) & 3;
    int chunk = (blk & 7) + 8 * (blk >> 5);
    bool isR = (g >= 2);
    const float* W = isR ? wr : wl;
    int cbase = (g & 1) * 64;
    f16x8 bf[4][6];
    float blv[4];
#pragma unroll
    for (int nt = 0; nt < 4; nt++) {
        int col = cbase + nt * 16 + l16;
        blv[nt] = isR ? bl[col] : 0.f;
#pragma unroll
        for (int ks = 0; ks < 6; ks++) {
            int kb = ks * 32 + q * 8;
            f16x8 b;
#pragma unroll
            for (int j = 0; j < 8; j++) {
                int k = kb + j;
                b[j] = (f16)((k < DIN) ? W[k * DH + col] : 0.f);
            }
            bf[nt][ks] = b;
        }
    }
    for (int mt = chunk * 4 + wave; mt < 6250; mt += 768) {
        const f16* yrow = Y + (long)(mt * 16 + l16) * 192;
        f32x4 acc[4];
#pragma unroll
        for (int nt = 0; nt < 4; nt++) acc[nt] = (f32x4){0.f, 0.f, 0.f, 0.f};
#pragma unroll
        for (int ks = 0; ks < 6; ks++) {
            f16x8 a = *((const f16x8*)(yrow + ks * 32 + q * 8));
#pragma unroll
            for (int nt = 0; nt < 4; nt++) acc[nt] = MFMA16(a, bf[nt][ks], acc[nt]);
        }
#pragma unroll
        for (int nt = 0; nt < 4; nt++) {
            int col = cbase + nt * 16 + l16;
#pragma unroll
            for (int r = 0; r < 4; r++) {
                int node = mt * 16 + q * 4 + r;
                if (isR)
                    x2[(long)node * DH + col] = (f16)(acc[nt][r] + blv[nt]);
                else
                    t_l[(long)node * DH + col] = (f16)acc[nt][r];
            }
        }
    }
}

// ==================== TAIL (both paths) ====================
__global__ __launch_bounds__(256) void sage_agg_kernel(const f16* __restrict__ t_l,
                                                       const int* __restrict__ rowptr,
                                                       const int* __restrict__ esrc,
                                                       f16* __restrict__ x2) {
    int wid = threadIdx.x >> 6, lane = threadIdx.x & 63;
    int i = blockIdx.x * 4 + wid;
    int r0 = rowptr[i], r1 = rowptr[i + 1];
    int quarter = lane >> 4, fq = lane & 15;
    float acc[8];
#pragma unroll
    for (int k = 0; k < 8; k++) acc[k] = 0.f;
    for (int e0 = r0; e0 < r1; e0 += 64) {
        int cnt = min(64, r1 - e0);
        int sn_v = (lane < cnt) ? esrc[e0 + lane] : 0;
        int jmax = (cnt + 3) >> 2;
        for (int j = 0; j < jmax; j++) {
            int idx = 4 * j + quarter;
            int sn = __shfl(sn_v, idx);
            float v = (idx < cnt) ? 1.f : 0.f;
            f16x8 p = *((const f16x8*)(t_l + ((long)sn << 7) + fq * 8));
#pragma unroll
            for (int k = 0; k < 8; k++) acc[k] = fmaf(v, (float)p[k], acc[k]);
        }
    }
#pragma unroll
    for (int k = 0; k < 8; k++) {
        acc[k] += __shfl_xor(acc[k], 16);
        acc[k] += __shfl_xor(acc[k], 32);
    }
    if (quarter == 0) {
        float inv = 1.f / fmaxf((float)(r1 - r0), 1.f);
        f16x8* xp = (f16x8*)(x2 + (long)i * DH + fq * 8);
        f16x8 pre = *xp;
        f16x8 o;
#pragma unroll
        for (int k = 0; k < 8; k++) o[k] = (f16)fmaxf((float)pre[k] + acc[k] * inv, 0.f);
        *xp = o;
    }
}

__global__ __launch_bounds__(256) void gat_h_kernel(const f16* __restrict__ x2,
                                                    const float* __restrict__ gw,
                                                    const float* __restrict__ att_s_w,
                                                    const float* __restrict__ att_d_w,
                                                    f16* __restrict__ h,
                                                    float* __restrict__ a_s,
                                                    float* __restrict__ a_d) {
    int tid = threadIdx.x, wave = tid >> 6, lane = tid & 63;
    int q = lane >> 4, l16 = lane & 15;
    f16x8 bf[4][4];
    float asw[4], adw[4];
#pragma unroll
    for (int nt = 0; nt < 4; nt++) {
        int col = nt * 16 + l16;
        asw[nt] = att_s_w[col];
        adw[nt] = att_d_w[col];
#pragma unroll
        for (int ks = 0; ks < 4; ks++) {
            int kb = ks * 32 + q * 8;
            f16x8 b;
#pragma unroll
            for (int j = 0; j < 8; j++) b[j] = (f16)gw[(kb + j) * DG + col];
            bf[nt][ks] = b;
        }
    }
    int stride = gridDim.x * 4;
    for (int mt = blockIdx.x * 4 + wave; mt < 6250; mt += stride) {
        const f16* xr = x2 + (long)(mt * 16 + l16) * DH;
        f32x4 acc[4];
#pragma unroll
        for (int nt = 0; nt < 4; nt++) acc[nt] = (f32x4){0.f, 0.f, 0.f, 0.f};
#pragma unroll
        for (int ks = 0; ks < 4; ks++) {
            f16x8 a = *((const f16x8*)(xr + ks * 32 + q * 8));
#pragma unroll
            for (int nt = 0; nt < 4; nt++) acc[nt] = MFMA16(a, bf[nt][ks], acc[nt]);
        }
#pragma unroll
        for (int r = 0; r < 4; r++) {
            int node = mt * 16 + q * 4 + r;
            float vs = 0.f, vd = 0.f;
#pragma unroll
            for (int nt = 0; nt < 4; nt++) {
                float hv = acc[nt][r];
                h[(long)node * DG + nt * 16 + l16] = (f16)hv;
                vs += hv * asw[nt];
                vd += hv * adw[nt];
            }
#pragma unroll
            for (int off = 1; off < 16; off <<= 1) {
                vs += __shfl_xor(vs, off);
                vd += __shfl_xor(vd, off);
            }
            if (l16 == 0) {
                a_s[node] = vs;
                a_d[node] = vd;
            }
        }
    }
}

__device__ __forceinline__ float leaky02(float v) { return v > 0.f ? v : 0.2f * v; }

__global__ __launch_bounds__(256) void gat_agg_kernel(const f16* __restrict__ h,
                                                      const float* __restrict__ a_s,
                                                      const float* __restrict__ a_d,
                                                      const int* __restrict__ rowptr,
                                                      const int* __restrict__ esrc,
                                                      const float* __restrict__ gat_b,
                                                      const float* __restrict__ cheb_w,
                                                      const float* __restrict__ cheb_b,
                                                      float* __restrict__ out) {
    int wid = threadIdx.x >> 6, lane = threadIdx.x & 63;
    int i = blockIdx.x * 4 + wid;
    int r0 = rowptr[i], r1 = rowptr[i + 1];
    int quarter = lane >> 4, fq = lane & 15;
    float adi = a_d[i];
    float acc[4] = {0.f, 0.f, 0.f, 0.f};
    float sv = 0.f;
    for (int e0 = r0; e0 < r1; e0 += 64) {
        int cnt = min(64, r1 - e0);
        int sn_v = (lane < cnt) ? esrc[e0 + lane] : 0;
        float ev = 0.f;
        if (lane < cnt) ev = __expf(leaky02(a_s[sn_v] + adi));
        sv += ev;
        int jmax = (cnt + 3) >> 2;
        for (int j = 0; j < jmax; j++) {
            int idx = 4 * j + quarter;
            int sn = __shfl(sn_v, idx);
            float w = __shfl(ev, idx);
            f16x4 p = *((const f16x4*)(h + ((long)sn << 6) + fq * 4));
#pragma unroll
            for (int k = 0; k < 4; k++) acc[k] = fmaf(w, (float)p[k], acc[k]);
        }
    }
#pragma unroll
    for (int off = 32; off > 0; off >>= 1) sv += __shfl_xor(sv, off);
#pragma unroll
    for (int k = 0; k < 4; k++) {
        acc[k] += __shfl_xor(acc[k], 16);
        acc[k] += __shfl_xor(acc[k], 32);
    }
    if (quarter == 0) {
        float wself = __expf(leaky02(a_s[i] + adi));
        float s = sv + wself;
        f16x4 ph = *((const f16x4*)(h + ((long)i << 6) + fq * 4));
        float4 gb = ((const float4*)gat_b)[fq];
        float4 cw = ((const float4*)cheb_w)[fq];
        float gbv[4] = {gb.x, gb.y, gb.z, gb.w};
        float cwv[4] = {cw.x, cw.y, cw.z, cw.w};
        float inv = 1.f / s;
        float z = 0.f;
#pragma unroll
        for (int k = 0; k < 4; k++) {
            float o = fmaxf(fmaf(wself, (float)ph[k], acc[k]) * inv + gbv[k], 0.f);
            z = fmaf(o, cwv[k], z);
        }
#pragma unroll
        for (int off = 8; off > 0; off >>= 1) z += __shfl_xor(z, off);
        if (fq == 0) out[i] = 1.f / (1.f + __expf(-(z + cheb_b[0])));
    }
}

extern "C" void kernel_launch(void* const* d_in, const int* in_sizes, int n_in,
                              void* d_out, int out_size, void* d_ws, size_t ws_size,
                              hipStream_t stream) {
    const float* x       = (const float*)d_in[0];
    const int*   eidx    = (const int*)d_in[1];
    const float* fb_w1   = (const float*)d_in[2];
    const float* fb_w2   = (const float*)d_in[3];
    const float* sage_wl = (const float*)d_in[4];
    const float* sage_bl = (const float*)d_in[5];
    const float* sage_wr = (const float*)d_in[6];
    const float* gat_w   = (const float*)d_in[7];
    const float* att_src = (const float*)d_in[8];
    const float* att_dst = (const float*)d_in[9];
    const float* gat_b   = (const float*)d_in[10];
    const float* cheb_w  = (const float*)d_in[11];
    const float* cheb_b  = (const float*)d_in[12];

    const int* src = eidx;
    const int* dst = eidx + N_EDGES;

    // workspace (~110 MB with aliasing)
    char* base = (char*)d_ws;
    f16* Xp = (f16*)base;                               //  0    .. 38.4 MB
    f16* H  = (f16*)(base + 38400000);                  // 38.4  .. 57.6 MB
    f16* Y  = (f16*)(base + 57600000);                  // 57.6  .. 96.0 MB
    f16* t_l = (f16*)base;                              // aliases Xp (dead after P5)
    f16* x2  = (f16*)(base + 25600000);                 // aliases Xp-tail+H
    f16* h   = Y;                                       // aliases Y (dead after P6)
    float* a_s = (float*)(base + 70400000);
    float* a_d = a_s + N_NODES;
    int* rowptr = (int*)(base + 96000000);              // 100,001
    int* cnt  = rowptr + (N_NODES + 1);                 // 100,000
    int* esrc = cnt + N_NODES;                          // 1,600,000
    int* rank = esrc + N_EDGES;                         // 1,600,000
    int* bsum = rank + N_EDGES;                         // 768 (coop uses 512, fallback 98)
    int* boff = bsum + 768;                             // 768

    hipMemsetAsync(cnt, 0, N_NODES * sizeof(int), stream);

    MegaArgs margs = {x, dst, src, fb_w1, fb_w2, sage_wl, sage_wr, sage_bl,
                      Xp, H, Y, t_l, x2, cnt, rank, rowptr, bsum, boff, esrc};
    void* kargs[] = {(void*)&margs};
    hipError_t cerr = hipLaunchCooperativeKernel((const void*)mega_kernel, dim3(512),
                                                 dim3(256), kargs, 0, stream);
    if (cerr != hipSuccess) {
        // fallback: R7-proven separate-kernel pipeline (idempotent: re-zero cnt)
        const int SCAN_BLOCKS = (N_NODES + 1023) / 1024;   // 98
        hipMemsetAsync(cnt, 0, N_NODES * sizeof(int), stream);
        rank_xpad_kernel<<<(N_NODES * 48) / 256, 256, 0, stream>>>(x, Xp, dst, cnt, rank);
        scan1_kernel<<<SCAN_BLOCKS, 1024, 0, stream>>>(cnt, rowptr, bsum);
        scan2_kernel<<<1, 64, 0, stream>>>(bsum, boff, rowptr, SCAN_BLOCKS);
        scan3_kernel<<<SCAN_BLOCKS, 1024, 0, stream>>>(rowptr, boff);
        h_fill_kernel<<<384, 256, 0, stream>>>(Xp, fb_w1, H, src, dst, rank, rowptr, esrc);
        y_kernel<<<768, 256, 0, stream>>>(Xp, H, fb_w2, Y);
        sage_lin_kernel<<<768, 256, 0, stream>>>(Y, sage_wl, sage_wr, sage_bl, t_l, x2);
    }

    sage_agg_kernel<<<N_NODES / 4, 256, 0, stream>>>(t_l, rowptr, esrc, x2);
    gat_h_kernel<<<392, 256, 0, stream>>>(x2, gat_w, att_src, att_dst, h, a_s, a_d);
    gat_agg_kernel<<<N_NODES / 4, 256, 0, stream>>>(h, a_s, a_d, rowptr, esrc, gat_b,
                                                    cheb_w, cheb_b, (float*)d_out);
}

// Round 10
// 492.078 us; speedup vs baseline: 2.7585x; 2.7585x over previous
//
#include <hip/hip_runtime.h>
#include <hip/hip_bf16.h>

#define N_NODES 100000
#define N_EDGES 1600000
#define DIN 165
#define DHID 82
#define DH 128
#define DG 64

typedef _Float16 f16;
typedef f16 f16x8 __attribute__((ext_vector_type(8)));
typedef f16 f16x4 __attribute__((ext_vector_type(4)));
typedef f16 f16x2 __attribute__((ext_vector_type(2)));
typedef float f32x4 __attribute__((ext_vector_type(4)));

#define MFMA16(a, b, c) __builtin_amdgcn_mfma_f32_16x16x32_f16(a, b, c, 0, 0, 0)

// MFMA 16x16x32 fragment layouts (verified, guide m89/m120):
//   A[m][k]: m = lane&15, k = (lane>>4)*8 + j
//   B[k][n]: n = lane&15, k = (lane>>4)*8 + j
//   D[m][n]: n = lane&15, m = (lane>>4)*4 + reg

// ============ K1: interleaved block-specialized rank atomics || xpad ============
// blk%4==0 -> rank (6250 blocks, 1.6M threads, full fabric-atomic parallelism)
// else     -> xpad (18750 blocks); roles interleaved so co-resident mix is 1:3
__global__ __launch_bounds__(256) void rank_xpad_kernel(const float* __restrict__ x,
                                                        f16* __restrict__ Xp,
                                                        const int* __restrict__ dst,
                                                        int* __restrict__ cnt,
                                                        int* __restrict__ rank) {
    int blk = blockIdx.x, tid = threadIdx.x;
    if ((blk & 3) == 0) {
        int e = (blk >> 2) * 256 + tid;                 // 0..1,599,999
        rank[e] = atomicAdd(&cnt[dst[e]], 1);
    } else {
        int xb = blk - (blk >> 2) - 1;                  // 0..18,749
        int gid = xb * 256 + tid;                       // 0..4,799,999
        int node = gid / 48, g = gid % 48;
        int col0 = g * 4;
        f16x4 o;
#pragma unroll
        for (int j = 0; j < 4; j++) {
            int c = col0 + j;
            o[j] = (f16)((c < DIN) ? x[(long)node * DIN + c] : 0.f);
        }
        *((f16x4*)(Xp + (long)node * 192 + col0)) = o;
    }
}

// ============ K2: fused hierarchical scan (single dispatch, last-block top scan) ============
// rowptr[i] = chunk-local exclusive prefix; boff[c] = global offset of chunk c.
// Consumers use rowptr[i] + boff[i>>10].
__global__ __launch_bounds__(1024) void scan_kernel(const int* __restrict__ cnt,
                                                    int* __restrict__ rowptr,
                                                    int* __restrict__ bsum,
                                                    int* __restrict__ boff,
                                                    int* __restrict__ arrived) {
    __shared__ int wsum[16];
    __shared__ int lastflag;
    int tid = threadIdx.x, lane = tid & 63, wid = tid >> 6;
    int blk = blockIdx.x;
    int i = blk * 1024 + tid;
    int v = (i < N_NODES) ? cnt[i] : 0;
    int xv = v;
#pragma unroll
    for (int off = 1; off < 64; off <<= 1) {
        int t = __shfl_up(xv, off);
        if (lane >= off) xv += t;
    }
    if (lane == 63) wsum[wid] = xv;
    __syncthreads();
    if (wid == 0 && lane < 16) {
        int wv = wsum[lane];
#pragma unroll
        for (int off = 1; off < 16; off <<= 1) {
            int t = __shfl_up(wv, off);
            if (lane >= off) wv += t;
        }
        wsum[lane] = wv;
    }
    __syncthreads();
    int off0 = wid ? wsum[wid - 1] : 0;
    if (i <= N_NODES) rowptr[i] = off0 + xv - v;  // chunk-local exclusive
    if (tid == 1023) bsum[blk] = off0 + xv;       // chunk total
    __threadfence();                              // release bsum/rowptr
    if (tid == 0) {
        int old = atomicAdd(arrived, 1);
        lastflag = (old == 97);
    }
    __syncthreads();
    if (lastflag && wid == 0) {
        __threadfence();                          // acquire
        int c = 0;
        for (int base = 0; base < 98; base += 64) {
            int idx = base + lane;
            int bv = 0;
            if (idx < 98)
                bv = __hip_atomic_load(&bsum[idx], __ATOMIC_RELAXED,
                                       __HIP_MEMORY_SCOPE_AGENT);
            int sv = bv;
#pragma unroll
            for (int off = 1; off < 64; off <<= 1) {
                int t = __shfl_up(sv, off);
                if (lane >= off) sv += t;
            }
            if (idx < 98) boff[idx] = c + sv - bv;
            c += __shfl(sv, 63);
        }
    }
}

// ============ K3: fill prologue (scatter, hidden) + H = relu(Xp@W1) ============
__global__ __launch_bounds__(256) void h_fill_kernel(const f16* __restrict__ Xp,
                                                     const float* __restrict__ w1,
                                                     f16* __restrict__ H,
                                                     const int* __restrict__ src,
                                                     const int* __restrict__ dst,
                                                     const int* __restrict__ rank,
                                                     const int* __restrict__ rowptr,
                                                     const int* __restrict__ boff,
                                                     int* __restrict__ esrc) {
    int tid = threadIdx.x, wave = tid >> 6, lane = tid & 63;
    {
        int tg = blockIdx.x * 256 + tid;
        for (int e = tg; e < N_EDGES; e += 384 * 256) {
            int d = dst[e];
            __builtin_nontemporal_store(src[e], &esrc[rowptr[d] + boff[d >> 10] + rank[e]]);
        }
    }
    int q = lane >> 4, l16 = lane & 15;
    int blk = blockIdx.x;
    int g = (blk >> 3) & 1;
    int chunk = (blk & 7) + 8 * (blk >> 4);
    int nbase = g * 48;
    f16x8 bf[3][6];
#pragma unroll
    for (int nt = 0; nt < 3; nt++) {
        int col = nbase + nt * 16 + l16;
#pragma unroll
        for (int ks = 0; ks < 6; ks++) {
            int kb = ks * 32 + q * 8;
            f16x8 b;
#pragma unroll
            for (int j = 0; j < 8; j++) {
                int k = kb + j;
                b[j] = (f16)((k < DIN && col < DHID) ? w1[k * DHID + col] : 0.f);
            }
            bf[nt][ks] = b;
        }
    }
    for (int mt = chunk * 4 + wave; mt < 6250; mt += 768) {
        const f16* xr = Xp + (long)(mt * 16 + l16) * 192;
        f32x4 acc[3];
#pragma unroll
        for (int nt = 0; nt < 3; nt++) acc[nt] = (f32x4){0.f, 0.f, 0.f, 0.f};
#pragma unroll
        for (int ks = 0; ks < 6; ks++) {
            f16x8 a = *((const f16x8*)(xr + ks * 32 + q * 8));
#pragma unroll
            for (int nt = 0; nt < 3; nt++) acc[nt] = MFMA16(a, bf[nt][ks], acc[nt]);
        }
#pragma unroll
        for (int nt = 0; nt < 3; nt++) {
            int col = nbase + nt * 16 + l16;
#pragma unroll
            for (int r = 0; r < 4; r++) {
                int node = mt * 16 + q * 4 + r;
                H[(long)node * 96 + col] = (f16)fmaxf(acc[nt][r], 0.f);
            }
        }
    }
}

// ============ K4: Y[N,192] f16 = Xp * sigmoid(2*(H @ W2pad)) ============
__global__ __launch_bounds__(256) void y_kernel(const f16* __restrict__ Xp,
                                                const f16* __restrict__ H,
                                                const float* __restrict__ w2,
                                                f16* __restrict__ Y) {
    int tid = threadIdx.x, wave = tid >> 6, lane = tid & 63;
    int q = lane >> 4, l16 = lane & 15;
    int blk = blockIdx.x;
    int g = (blk >> 3) & 3;
    int chunk = (blk & 7) + 8 * (blk >> 5);
    int nbase = g * 48;
    f16x8 bf[3][3];
#pragma unroll
    for (int nt = 0; nt < 3; nt++) {
        int col = nbase + nt * 16 + l16;
#pragma unroll
        for (int ks = 0; ks < 3; ks++) {
            int kb = ks * 32 + q * 8;
            f16x8 b;
#pragma unroll
            for (int j = 0; j < 8; j++) {
                int k = kb + j;
                b[j] = (f16)((k < DHID && col < DIN) ? w2[k * DIN + col] : 0.f);
            }
            bf[nt][ks] = b;
        }
    }
    for (int mt = chunk * 4 + wave; mt < 6250; mt += 768) {
        const f16* hr = H + (long)(mt * 16 + l16) * 96;
        f32x4 acc[3];
#pragma unroll
        for (int nt = 0; nt < 3; nt++) acc[nt] = (f32x4){0.f, 0.f, 0.f, 0.f};
#pragma unroll
        for (int ks = 0; ks < 3; ks++) {
            f16x8 a = *((const f16x8*)(hr + ks * 32 + q * 8));
#pragma unroll
            for (int nt = 0; nt < 3; nt++) acc[nt] = MFMA16(a, bf[nt][ks], acc[nt]);
        }
#pragma unroll
        for (int nt = 0; nt < 3; nt++) {
            int col = nbase + nt * 16 + l16;
#pragma unroll
            for (int r = 0; r < 4; r++) {
                int node = mt * 16 + q * 4 + r;
                float gg = 1.f / (1.f + __expf(-2.f * acc[nt][r]));
                float xv = (float)Xp[(long)node * 192 + col];
                Y[(long)node * 192 + col] = (f16)(xv * gg);
            }
        }
    }
}

// ============ K5: t_l = Y@WL (f16) ; x2pre = Y@WR + bl (f16) ============
__global__ __launch_bounds__(256) void sage_lin_kernel(const f16* __restrict__ Y,
                                                       const float* __restrict__ wl,
                                                       const float* __restrict__ wr,
                                                       const float* __restrict__ bl,
                                                       f16* __restrict__ t_l,
                                                       f16* __restrict__ x2) {
    int tid = threadIdx.x, wave = tid >> 6, lane = tid & 63;
    int q = lane >> 4, l16 = lane & 15;
    int blk = blockIdx.x;
    int g = (blk >> 3) & 3;
    int chunk = (blk & 7) + 8 * (blk >> 5);
    bool isR = (g >= 2);
    const float* W = isR ? wr : wl;
    int cbase = (g & 1) * 64;
    f16x8 bf[4][6];
    float blv[4];
#pragma unroll
    for (int nt = 0; nt < 4; nt++) {
        int col = cbase + nt * 16 + l16;
        blv[nt] = isR ? bl[col] : 0.f;
#pragma unroll
        for (int ks = 0; ks < 6; ks++) {
            int kb = ks * 32 + q * 8;
            f16x8 b;
#pragma unroll
            for (int j = 0; j < 8; j++) {
                int k = kb + j;
                b[j] = (f16)((k < DIN) ? W[k * DH + col] : 0.f);
            }
            bf[nt][ks] = b;
        }
    }
    for (int mt = chunk * 4 + wave; mt < 6250; mt += 768) {
        const f16* yrow = Y + (long)(mt * 16 + l16) * 192;
        f32x4 acc[4];
#pragma unroll
        for (int nt = 0; nt < 4; nt++) acc[nt] = (f32x4){0.f, 0.f, 0.f, 0.f};
#pragma unroll
        for (int ks = 0; ks < 6; ks++) {
            f16x8 a = *((const f16x8*)(yrow + ks * 32 + q * 8));
#pragma unroll
            for (int nt = 0; nt < 4; nt++) acc[nt] = MFMA16(a, bf[nt][ks], acc[nt]);
        }
#pragma unroll
        for (int nt = 0; nt < 4; nt++) {
            int col = cbase + nt * 16 + l16;
#pragma unroll
            for (int r = 0; r < 4; r++) {
                int node = mt * 16 + q * 4 + r;
                if (isR)
                    x2[(long)node * DH + col] = (f16)(acc[nt][r] + blv[nt]);
                else
                    t_l[(long)node * DH + col] = (f16)acc[nt][r];
            }
        }
    }
}

// ============ K6: SAGE aggregate: x2 = relu(x2pre + mean(t_l[src])) ============
__global__ __launch_bounds__(256) void sage_agg_kernel(const f16* __restrict__ t_l,
                                                       const int* __restrict__ rowptr,
                                                       const int* __restrict__ boff,
                                                       const int* __restrict__ esrc,
                                                       f16* __restrict__ x2) {
    int wid = threadIdx.x >> 6, lane = threadIdx.x & 63;
    int i = blockIdx.x * 4 + wid;
    int r0 = rowptr[i] + boff[i >> 10];
    int r1 = rowptr[i + 1] + boff[(i + 1) >> 10];
    int quarter = lane >> 4, fq = lane & 15;
    float acc[8];
#pragma unroll
    for (int k = 0; k < 8; k++) acc[k] = 0.f;
    for (int e0 = r0; e0 < r1; e0 += 64) {
        int cnt = min(64, r1 - e0);
        int sn_v = (lane < cnt) ? esrc[e0 + lane] : 0;
        int jmax = (cnt + 3) >> 2;
        for (int j = 0; j < jmax; j++) {
            int idx = 4 * j + quarter;
            int sn = __shfl(sn_v, idx);
            float v = (idx < cnt) ? 1.f : 0.f;
            f16x8 p = *((const f16x8*)(t_l + ((long)sn << 7) + fq * 8));
#pragma unroll
            for (int k = 0; k < 8; k++) acc[k] = fmaf(v, (float)p[k], acc[k]);
        }
    }
#pragma unroll
    for (int k = 0; k < 8; k++) {
        acc[k] += __shfl_xor(acc[k], 16);
        acc[k] += __shfl_xor(acc[k], 32);
    }
    if (quarter == 0) {
        float inv = 1.f / fmaxf((float)(r1 - r0), 1.f);
        f16x8* xp = (f16x8*)(x2 + (long)i * DH + fq * 8);
        f16x8 pre = *xp;
        f16x8 o;
#pragma unroll
        for (int k = 0; k < 8; k++) o[k] = (f16)fmaxf((float)pre[k] + acc[k] * inv, 0.f);
        *xp = o;
    }
}

// ============ K7: h = x2@gw (f16), a_s/a_d row-dots ============
__global__ __launch_bounds__(256) void gat_h_kernel(const f16* __restrict__ x2,
                                                    const float* __restrict__ gw,
                                                    const float* __restrict__ att_s_w,
                                                    const float* __restrict__ att_d_w,
                                                    f16* __restrict__ h,
                                                    float* __restrict__ a_s,
                                                    float* __restrict__ a_d) {
    int tid = threadIdx.x, wave = tid >> 6, lane = tid & 63;
    int q = lane >> 4, l16 = lane & 15;
    f16x8 bf[4][4];
    float asw[4], adw[4];
#pragma unroll
    for (int nt = 0; nt < 4; nt++) {
        int col = nt * 16 + l16;
        asw[nt] = att_s_w[col];
        adw[nt] = att_d_w[col];
#pragma unroll
        for (int ks = 0; ks < 4; ks++) {
            int kb = ks * 32 + q * 8;
            f16x8 b;
#pragma unroll
            for (int j = 0; j < 8; j++) b[j] = (f16)gw[(kb + j) * DG + col];
            bf[nt][ks] = b;
        }
    }
    int stride = gridDim.x * 4;
    for (int mt = blockIdx.x * 4 + wave; mt < 6250; mt += stride) {
        const f16* xr = x2 + (long)(mt * 16 + l16) * DH;
        f32x4 acc[4];
#pragma unroll
        for (int nt = 0; nt < 4; nt++) acc[nt] = (f32x4){0.f, 0.f, 0.f, 0.f};
#pragma unroll
        for (int ks = 0; ks < 4; ks++) {
            f16x8 a = *((const f16x8*)(xr + ks * 32 + q * 8));
#pragma unroll
            for (int nt = 0; nt < 4; nt++) acc[nt] = MFMA16(a, bf[nt][ks], acc[nt]);
        }
#pragma unroll
        for (int r = 0; r < 4; r++) {
            int node = mt * 16 + q * 4 + r;
            float vs = 0.f, vd = 0.f;
#pragma unroll
            for (int nt = 0; nt < 4; nt++) {
                float hv = acc[nt][r];
                h[(long)node * DG + nt * 16 + l16] = (f16)hv;
                vs += hv * asw[nt];
                vd += hv * adw[nt];
            }
#pragma unroll
            for (int off = 1; off < 16; off <<= 1) {
                vs += __shfl_xor(vs, off);
                vd += __shfl_xor(vd, off);
            }
            if (l16 == 0) {
                a_s[node] = vs;
                a_d[node] = vd;
            }
        }
    }
}

// ============ K8: GAT aggregate + bias + relu + Cheb(64->1) + sigmoid ============
__device__ __forceinline__ float leaky02(float v) { return v > 0.f ? v : 0.2f * v; }

__global__ __launch_bounds__(256) void gat_agg_kernel(const f16* __restrict__ h,
                                                      const float* __restrict__ a_s,
                                                      const float* __restrict__ a_d,
                                                      const int* __restrict__ rowptr,
                                                      const int* __restrict__ boff,
                                                      const int* __restrict__ esrc,
                                                      const float* __restrict__ gat_b,
                                                      const float* __restrict__ cheb_w,
                                                      const float* __restrict__ cheb_b,
                                                      float* __restrict__ out) {
    int wid = threadIdx.x >> 6, lane = threadIdx.x & 63;
    int i = blockIdx.x * 4 + wid;
    int r0 = rowptr[i] + boff[i >> 10];
    int r1 = rowptr[i + 1] + boff[(i + 1) >> 10];
    int quarter = lane >> 4, fq = lane & 15;
    float adi = a_d[i];
    float acc[4] = {0.f, 0.f, 0.f, 0.f};
    float sv = 0.f;
    for (int e0 = r0; e0 < r1; e0 += 64) {
        int cnt = min(64, r1 - e0);
        int sn_v = (lane < cnt) ? esrc[e0 + lane] : 0;
        float ev = 0.f;
        if (lane < cnt) ev = __expf(leaky02(a_s[sn_v] + adi));
        sv += ev;
        int jmax = (cnt + 3) >> 2;
        for (int j = 0; j < jmax; j++) {
            int idx = 4 * j + quarter;
            int sn = __shfl(sn_v, idx);
            float w = __shfl(ev, idx);
            f16x4 p = *((const f16x4*)(h + ((long)sn << 6) + fq * 4));
#pragma unroll
            for (int k = 0; k < 4; k++) acc[k] = fmaf(w, (float)p[k], acc[k]);
        }
    }
#pragma unroll
    for (int off = 32; off > 0; off >>= 1) sv += __shfl_xor(sv, off);
#pragma unroll
    for (int k = 0; k < 4; k++) {
        acc[k] += __shfl_xor(acc[k], 16);
        acc[k] += __shfl_xor(acc[k], 32);
    }
    if (quarter == 0) {
        float wself = __expf(leaky02(a_s[i] + adi));
        float s = sv + wself;
        f16x4 ph = *((const f16x4*)(h + ((long)i << 6) + fq * 4));
        float4 gb = ((const float4*)gat_b)[fq];
        float4 cw = ((const float4*)cheb_w)[fq];
        float gbv[4] = {gb.x, gb.y, gb.z, gb.w};
        float cwv[4] = {cw.x, cw.y, cw.z, cw.w};
        float inv = 1.f / s;
        float z = 0.f;
#pragma unroll
        for (int k = 0; k < 4; k++) {
            float o = fmaxf(fmaf(wself, (float)ph[k], acc[k]) * inv + gbv[k], 0.f);
            z = fmaf(o, cwv[k], z);
        }
#pragma unroll
        for (int off = 8; off > 0; off >>= 1) z += __shfl_xor(z, off);
        if (fq == 0) out[i] = 1.f / (1.f + __expf(-(z + cheb_b[0])));
    }
}

extern "C" void kernel_launch(void* const* d_in, const int* in_sizes, int n_in,
                              void* d_out, int out_size, void* d_ws, size_t ws_size,
                              hipStream_t stream) {
    const float* x       = (const float*)d_in[0];
    const int*   eidx    = (const int*)d_in[1];
    const float* fb_w1   = (const float*)d_in[2];
    const float* fb_w2   = (const float*)d_in[3];
    const float* sage_wl = (const float*)d_in[4];
    const float* sage_bl = (const float*)d_in[5];
    const float* sage_wr = (const float*)d_in[6];
    const float* gat_w   = (const float*)d_in[7];
    const float* att_src = (const float*)d_in[8];
    const float* att_dst = (const float*)d_in[9];
    const float* gat_b   = (const float*)d_in[10];
    const float* cheb_w  = (const float*)d_in[11];
    const float* cheb_b  = (const float*)d_in[12];

    const int* src = eidx;
    const int* dst = eidx + N_EDGES;

    // workspace (~110 MB with aliasing)
    char* base = (char*)d_ws;
    f16* Xp = (f16*)base;                               //  0    .. 38.4 MB
    f16* H  = (f16*)(base + 38400000);                  // 38.4  .. 57.6 MB
    f16* Y  = (f16*)(base + 57600000);                  // 57.6  .. 96.0 MB
    f16* t_l = (f16*)base;                              // aliases Xp (dead after y)
    f16* x2  = (f16*)(base + 25600000);                 // aliases Xp-tail+H
    f16* h   = Y;                                       // aliases Y (dead after sage_lin)
    float* a_s = (float*)(base + 70400000);
    float* a_d = a_s + N_NODES;
    int* rowptr  = (int*)(base + 96000000);             // 100,001
    int* cnt     = rowptr + (N_NODES + 1);              // 100,000
    int* arrived = cnt + N_NODES;                       // 1 (covered by memset below)
    int* esrc    = arrived + 1;                         // 1,600,000
    int* rank    = esrc + N_EDGES;                      // 1,600,000
    int* bsum    = rank + N_EDGES;                      // 98
    int* boff    = bsum + 128;                          // 98

    hipMemsetAsync(cnt, 0, (N_NODES + 1) * sizeof(int), stream);  // cnt + arrived

    rank_xpad_kernel<<<25000, 256, 0, stream>>>(x, Xp, dst, cnt, rank);
    scan_kernel<<<98, 1024, 0, stream>>>(cnt, rowptr, bsum, boff, arrived);
    h_fill_kernel<<<384, 256, 0, stream>>>(Xp, fb_w1, H, src, dst, rank, rowptr, boff, esrc);
    y_kernel<<<768, 256, 0, stream>>>(Xp, H, fb_w2, Y);
    sage_lin_kernel<<<768, 256, 0, stream>>>(Y, sage_wl, sage_wr, sage_bl, t_l, x2);
    sage_agg_kernel<<<N_NODES / 4, 256, 0, stream>>>(t_l, rowptr, boff, esrc, x2);
    gat_h_kernel<<<392, 256, 0, stream>>>(x2, gat_w, att_src, att_dst, h, a_s, a_d);
    gat_agg_kernel<<<N_NODES / 4, 256, 0, stream>>>(h, a_s, a_d, rowptr, boff, esrc, gat_b,
                                                    cheb_w, cheb_b, (float*)d_out);
}

// Round 11
// 490.434 us; speedup vs baseline: 2.7678x; 1.0034x over previous
//
#include <hip/hip_runtime.h>
#include <hip/hip_bf16.h>

#define N_NODES 100000
#define N_EDGES 1600000
#define DIN 165
#define DHID 82
#define DH 128
#define DG 64

typedef _Float16 f16;
typedef f16 f16x8 __attribute__((ext_vector_type(8)));
typedef f16 f16x4 __attribute__((ext_vector_type(4)));
typedef f16 f16x2 __attribute__((ext_vector_type(2)));
typedef float f32x4 __attribute__((ext_vector_type(4)));

#define MFMA16(a, b, c) __builtin_amdgcn_mfma_f32_16x16x32_f16(a, b, c, 0, 0, 0)

// MFMA 16x16x32 fragment layouts (verified, guide m89/m120):
//   A[m][k]: m = lane&15, k = (lane>>4)*8 + j
//   B[k][n]: n = lane&15, k = (lane>>4)*8 + j
//   D[m][n]: n = lane&15, m = (lane>>4)*4 + reg

// ============ K1: interleaved block-specialized rank atomics || xpad ============
// blk%4==0 -> rank into replica (rb&7) of cnt8 (8x lower line contention)
// else     -> xpad (18750 blocks)
__global__ __launch_bounds__(256) void rank_xpad_kernel(const float* __restrict__ x,
                                                        f16* __restrict__ Xp,
                                                        const int* __restrict__ dst,
                                                        int* __restrict__ cnt8,
                                                        int* __restrict__ rank) {
    int blk = blockIdx.x, tid = threadIdx.x;
    if ((blk & 3) == 0) {
        int rb = blk >> 2;                              // 0..6249
        int e = rb * 256 + tid;                         // 0..1,599,999
        int r = rb & 7;                                 // replica
        rank[e] = atomicAdd(&cnt8[r * N_NODES + dst[e]], 1);
    } else {
        int xb = blk - (blk >> 2) - 1;                  // 0..18,749
        int gid = xb * 256 + tid;                       // 0..4,799,999
        int node = gid / 48, g = gid % 48;
        int col0 = g * 4;
        f16x4 o;
#pragma unroll
        for (int j = 0; j < 4; j++) {
            int c = col0 + j;
            o[j] = (f16)((c < DIN) ? x[(long)node * DIN + c] : 0.f);
        }
        *((f16x4*)(Xp + (long)node * 192 + col0)) = o;
    }
}

// ============ K2: fused scan (single dispatch, last-block top scan) ============
// merges the 8 count replicas: roff8[r][i] = exclusive prefix over replicas,
// rowptr[i] = chunk-local exclusive prefix of node totals, boff[c] = chunk offset.
__global__ __launch_bounds__(1024) void scan_kernel(const int* __restrict__ cnt8,
                                                    int* __restrict__ roff8,
                                                    int* __restrict__ rowptr,
                                                    int* __restrict__ bsum,
                                                    int* __restrict__ boff,
                                                    int* __restrict__ arrived) {
    __shared__ int wsum[16];
    __shared__ int lastflag;
    int tid = threadIdx.x, lane = tid & 63, wid = tid >> 6;
    int blk = blockIdx.x;
    int i = blk * 1024 + tid;
    int v = 0;
    if (i < N_NODES) {
        int run = 0;
#pragma unroll
        for (int r = 0; r < 8; r++) {
            int c = cnt8[r * N_NODES + i];
            roff8[r * N_NODES + i] = run;
            run += c;
        }
        v = run;
    }
    int xv = v;
#pragma unroll
    for (int off = 1; off < 64; off <<= 1) {
        int t = __shfl_up(xv, off);
        if (lane >= off) xv += t;
    }
    if (lane == 63) wsum[wid] = xv;
    __syncthreads();
    if (wid == 0 && lane < 16) {
        int wv = wsum[lane];
#pragma unroll
        for (int off = 1; off < 16; off <<= 1) {
            int t = __shfl_up(wv, off);
            if (lane >= off) wv += t;
        }
        wsum[lane] = wv;
    }
    __syncthreads();
    int off0 = wid ? wsum[wid - 1] : 0;
    if (i <= N_NODES) rowptr[i] = off0 + xv - v;  // chunk-local exclusive
    if (tid == 1023) bsum[blk] = off0 + xv;       // chunk total
    __threadfence();                              // release bsum/rowptr/roff8
    if (tid == 0) {
        int old = atomicAdd(arrived, 1);
        lastflag = (old == 97);
    }
    __syncthreads();
    if (lastflag && wid == 0) {
        __threadfence();                          // acquire
        int c = 0;
        for (int base = 0; base < 98; base += 64) {
            int idx = base + lane;
            int bv = 0;
            if (idx < 98)
                bv = __hip_atomic_load(&bsum[idx], __ATOMIC_RELAXED,
                                       __HIP_MEMORY_SCOPE_AGENT);
            int sv = bv;
#pragma unroll
            for (int off = 1; off < 64; off <<= 1) {
                int t = __shfl_up(sv, off);
                if (lane >= off) sv += t;
            }
            if (idx < 98) boff[idx] = c + sv - bv;
            c += __shfl(sv, 63);
        }
    }
}

// ============ K3: fill prologue (scatter, hidden) + H = relu(Xp@W1) ============
__global__ __launch_bounds__(256) void h_fill_kernel(const f16* __restrict__ Xp,
                                                     const float* __restrict__ w1,
                                                     f16* __restrict__ H,
                                                     const int* __restrict__ src,
                                                     const int* __restrict__ dst,
                                                     const int* __restrict__ rank,
                                                     const int* __restrict__ rowptr,
                                                     const int* __restrict__ boff,
                                                     const int* __restrict__ roff8,
                                                     int* __restrict__ esrc) {
    int tid = threadIdx.x, wave = tid >> 6, lane = tid & 63;
    {
        int tg = blockIdx.x * 256 + tid;
        for (int e = tg; e < N_EDGES; e += 384 * 256) {
            int d = dst[e];
            int r = (e >> 8) & 7;                 // replica used in rank pass
            int pos = rowptr[d] + boff[d >> 10] + roff8[r * N_NODES + d] + rank[e];
            __builtin_nontemporal_store(src[e], &esrc[pos]);
        }
    }
    int q = lane >> 4, l16 = lane & 15;
    int blk = blockIdx.x;
    int g = (blk >> 3) & 1;
    int chunk = (blk & 7) + 8 * (blk >> 4);
    int nbase = g * 48;
    f16x8 bf[3][6];
#pragma unroll
    for (int nt = 0; nt < 3; nt++) {
        int col = nbase + nt * 16 + l16;
#pragma unroll
        for (int ks = 0; ks < 6; ks++) {
            int kb = ks * 32 + q * 8;
            f16x8 b;
#pragma unroll
            for (int j = 0; j < 8; j++) {
                int k = kb + j;
                b[j] = (f16)((k < DIN && col < DHID) ? w1[k * DHID + col] : 0.f);
            }
            bf[nt][ks] = b;
        }
    }
    for (int mt = chunk * 4 + wave; mt < 6250; mt += 768) {
        const f16* xr = Xp + (long)(mt * 16 + l16) * 192;
        f32x4 acc[3];
#pragma unroll
        for (int nt = 0; nt < 3; nt++) acc[nt] = (f32x4){0.f, 0.f, 0.f, 0.f};
#pragma unroll
        for (int ks = 0; ks < 6; ks++) {
            f16x8 a = *((const f16x8*)(xr + ks * 32 + q * 8));
#pragma unroll
            for (int nt = 0; nt < 3; nt++) acc[nt] = MFMA16(a, bf[nt][ks], acc[nt]);
        }
#pragma unroll
        for (int nt = 0; nt < 3; nt++) {
            int col = nbase + nt * 16 + l16;
#pragma unroll
            for (int r = 0; r < 4; r++) {
                int node = mt * 16 + q * 4 + r;
                H[(long)node * 96 + col] = (f16)fmaxf(acc[nt][r], 0.f);
            }
        }
    }
}

// ============ K4: Y[N,192] f16 = Xp * sigmoid(2*(H @ W2pad)) ============
__global__ __launch_bounds__(256) void y_kernel(const f16* __restrict__ Xp,
                                                const f16* __restrict__ H,
                                                const float* __restrict__ w2,
                                                f16* __restrict__ Y) {
    int tid = threadIdx.x, wave = tid >> 6, lane = tid & 63;
    int q = lane >> 4, l16 = lane & 15;
    int blk = blockIdx.x;
    int g = (blk >> 3) & 3;
    int chunk = (blk & 7) + 8 * (blk >> 5);
    int nbase = g * 48;
    f16x8 bf[3][3];
#pragma unroll
    for (int nt = 0; nt < 3; nt++) {
        int col = nbase + nt * 16 + l16;
#pragma unroll
        for (int ks = 0; ks < 3; ks++) {
            int kb = ks * 32 + q * 8;
            f16x8 b;
#pragma unroll
            for (int j = 0; j < 8; j++) {
                int k = kb + j;
                b[j] = (f16)((k < DHID && col < DIN) ? w2[k * DIN + col] : 0.f);
            }
            bf[nt][ks] = b;
        }
    }
    for (int mt = chunk * 4 + wave; mt < 6250; mt += 768) {
        const f16* hr = H + (long)(mt * 16 + l16) * 96;
        f32x4 acc[3];
#pragma unroll
        for (int nt = 0; nt < 3; nt++) acc[nt] = (f32x4){0.f, 0.f, 0.f, 0.f};
#pragma unroll
        for (int ks = 0; ks < 3; ks++) {
            f16x8 a = *((const f16x8*)(hr + ks * 32 + q * 8));
#pragma unroll
            for (int nt = 0; nt < 3; nt++) acc[nt] = MFMA16(a, bf[nt][ks], acc[nt]);
        }
#pragma unroll
        for (int nt = 0; nt < 3; nt++) {
            int col = nbase + nt * 16 + l16;
#pragma unroll
            for (int r = 0; r < 4; r++) {
                int node = mt * 16 + q * 4 + r;
                float gg = 1.f / (1.f + __expf(-2.f * acc[nt][r]));
                float xv = (float)Xp[(long)node * 192 + col];
                Y[(long)node * 192 + col] = (f16)(xv * gg);
            }
        }
    }
}

// ============ K5: t_l = Y@WL (f16) ; x2pre = Y@WR + bl (f16) ============
__global__ __launch_bounds__(256) void sage_lin_kernel(const f16* __restrict__ Y,
                                                       const float* __restrict__ wl,
                                                       const float* __restrict__ wr,
                                                       const float* __restrict__ bl,
                                                       f16* __restrict__ t_l,
                                                       f16* __restrict__ x2) {
    int tid = threadIdx.x, wave = tid >> 6, lane = tid & 63;
    int q = lane >> 4, l16 = lane & 15;
    int blk = blockIdx.x;
    int g = (blk >> 3) & 3;
    int chunk = (blk & 7) + 8 * (blk >> 5);
    bool isR = (g >= 2);
    const float* W = isR ? wr : wl;
    int cbase = (g & 1) * 64;
    f16x8 bf[4][6];
    float blv[4];
#pragma unroll
    for (int nt = 0; nt < 4; nt++) {
        int col = cbase + nt * 16 + l16;
        blv[nt] = isR ? bl[col] : 0.f;
#pragma unroll
        for (int ks = 0; ks < 6; ks++) {
            int kb = ks * 32 + q * 8;
            f16x8 b;
#pragma unroll
            for (int j = 0; j < 8; j++) {
                int k = kb + j;
                b[j] = (f16)((k < DIN) ? W[k * DH + col] : 0.f);
            }
            bf[nt][ks] = b;
        }
    }
    for (int mt = chunk * 4 + wave; mt < 6250; mt += 768) {
        const f16* yrow = Y + (long)(mt * 16 + l16) * 192;
        f32x4 acc[4];
#pragma unroll
        for (int nt = 0; nt < 4; nt++) acc[nt] = (f32x4){0.f, 0.f, 0.f, 0.f};
#pragma unroll
        for (int ks = 0; ks < 6; ks++) {
            f16x8 a = *((const f16x8*)(yrow + ks * 32 + q * 8));
#pragma unroll
            for (int nt = 0; nt < 4; nt++) acc[nt] = MFMA16(a, bf[nt][ks], acc[nt]);
        }
#pragma unroll
        for (int nt = 0; nt < 4; nt++) {
            int col = cbase + nt * 16 + l16;
#pragma unroll
            for (int r = 0; r < 4; r++) {
                int node = mt * 16 + q * 4 + r;
                if (isR)
                    x2[(long)node * DH + col] = (f16)(acc[nt][r] + blv[nt]);
                else
                    t_l[(long)node * DH + col] = (f16)acc[nt][r];
            }
        }
    }
}

// ============ K6: SAGE aggregate: x2 = relu(x2pre + mean(t_l[src])) ============
__global__ __launch_bounds__(256) void sage_agg_kernel(const f16* __restrict__ t_l,
                                                       const int* __restrict__ rowptr,
                                                       const int* __restrict__ boff,
                                                       const int* __restrict__ esrc,
                                                       f16* __restrict__ x2) {
    int wid = threadIdx.x >> 6, lane = threadIdx.x & 63;
    int i = blockIdx.x * 4 + wid;
    int r0 = rowptr[i] + boff[i >> 10];
    int r1 = rowptr[i + 1] + boff[(i + 1) >> 10];
    int quarter = lane >> 4, fq = lane & 15;
    float acc[8];
#pragma unroll
    for (int k = 0; k < 8; k++) acc[k] = 0.f;
    for (int e0 = r0; e0 < r1; e0 += 64) {
        int cnt = min(64, r1 - e0);
        int sn_v = (lane < cnt) ? esrc[e0 + lane] : 0;
        int jmax = (cnt + 3) >> 2;
        for (int j = 0; j < jmax; j++) {
            int idx = 4 * j + quarter;
            int sn = __shfl(sn_v, idx);
            float v = (idx < cnt) ? 1.f : 0.f;
            f16x8 p = *((const f16x8*)(t_l + ((long)sn << 7) + fq * 8));
#pragma unroll
            for (int k = 0; k < 8; k++) acc[k] = fmaf(v, (float)p[k], acc[k]);
        }
    }
#pragma unroll
    for (int k = 0; k < 8; k++) {
        acc[k] += __shfl_xor(acc[k], 16);
        acc[k] += __shfl_xor(acc[k], 32);
    }
    if (quarter == 0) {
        float inv = 1.f / fmaxf((float)(r1 - r0), 1.f);
        f16x8* xp = (f16x8*)(x2 + (long)i * DH + fq * 8);
        f16x8 pre = *xp;
        f16x8 o;
#pragma unroll
        for (int k = 0; k < 8; k++) o[k] = (f16)fmaxf((float)pre[k] + acc[k] * inv, 0.f);
        *xp = o;
    }
}

// ============ K7: h = x2@gw (f16), a_s/a_d row-dots ============
__global__ __launch_bounds__(256) void gat_h_kernel(const f16* __restrict__ x2,
                                                    const float* __restrict__ gw,
                                                    const float* __restrict__ att_s_w,
                                                    const float* __restrict__ att_d_w,
                                                    f16* __restrict__ h,
                                                    float* __restrict__ a_s,
                                                    float* __restrict__ a_d) {
    int tid = threadIdx.x, wave = tid >> 6, lane = tid & 63;
    int q = lane >> 4, l16 = lane & 15;
    f16x8 bf[4][4];
    float asw[4], adw[4];
#pragma unroll
    for (int nt = 0; nt < 4; nt++) {
        int col = nt * 16 + l16;
        asw[nt] = att_s_w[col];
        adw[nt] = att_d_w[col];
#pragma unroll
        for (int ks = 0; ks < 4; ks++) {
            int kb = ks * 32 + q * 8;
            f16x8 b;
#pragma unroll
            for (int j = 0; j < 8; j++) b[j] = (f16)gw[(kb + j) * DG + col];
            bf[nt][ks] = b;
        }
    }
    int stride = gridDim.x * 4;
    for (int mt = blockIdx.x * 4 + wave; mt < 6250; mt += stride) {
        const f16* xr = x2 + (long)(mt * 16 + l16) * DH;
        f32x4 acc[4];
#pragma unroll
        for (int nt = 0; nt < 4; nt++) acc[nt] = (f32x4){0.f, 0.f, 0.f, 0.f};
#pragma unroll
        for (int ks = 0; ks < 4; ks++) {
            f16x8 a = *((const f16x8*)(xr + ks * 32 + q * 8));
#pragma unroll
            for (int nt = 0; nt < 4; nt++) acc[nt] = MFMA16(a, bf[nt][ks], acc[nt]);
        }
#pragma unroll
        for (int r = 0; r < 4; r++) {
            int node = mt * 16 + q * 4 + r;
            float vs = 0.f, vd = 0.f;
#pragma unroll
            for (int nt = 0; nt < 4; nt++) {
                float hv = acc[nt][r];
                h[(long)node * DG + nt * 16 + l16] = (f16)hv;
                vs += hv * asw[nt];
                vd += hv * adw[nt];
            }
#pragma unroll
            for (int off = 1; off < 16; off <<= 1) {
                vs += __shfl_xor(vs, off);
                vd += __shfl_xor(vd, off);
            }
            if (l16 == 0) {
                a_s[node] = vs;
                a_d[node] = vd;
            }
        }
    }
}

// ============ K8: GAT aggregate + bias + relu + Cheb(64->1) + sigmoid ============
__device__ __forceinline__ float leaky02(float v) { return v > 0.f ? v : 0.2f * v; }

__global__ __launch_bounds__(256) void gat_agg_kernel(const f16* __restrict__ h,
                                                      const float* __restrict__ a_s,
                                                      const float* __restrict__ a_d,
                                                      const int* __restrict__ rowptr,
                                                      const int* __restrict__ boff,
                                                      const int* __restrict__ esrc,
                                                      const float* __restrict__ gat_b,
                                                      const float* __restrict__ cheb_w,
                                                      const float* __restrict__ cheb_b,
                                                      float* __restrict__ out) {
    int wid = threadIdx.x >> 6, lane = threadIdx.x & 63;
    int i = blockIdx.x * 4 + wid;
    int r0 = rowptr[i] + boff[i >> 10];
    int r1 = rowptr[i + 1] + boff[(i + 1) >> 10];
    int quarter = lane >> 4, fq = lane & 15;
    float adi = a_d[i];
    float acc[4] = {0.f, 0.f, 0.f, 0.f};
    float sv = 0.f;
    for (int e0 = r0; e0 < r1; e0 += 64) {
        int cnt = min(64, r1 - e0);
        int sn_v = (lane < cnt) ? esrc[e0 + lane] : 0;
        float ev = 0.f;
        if (lane < cnt) ev = __expf(leaky02(a_s[sn_v] + adi));
        sv += ev;
        int jmax = (cnt + 3) >> 2;
        for (int j = 0; j < jmax; j++) {
            int idx = 4 * j + quarter;
            int sn = __shfl(sn_v, idx);
            float w = __shfl(ev, idx);
            f16x4 p = *((const f16x4*)(h + ((long)sn << 6) + fq * 4));
#pragma unroll
            for (int k = 0; k < 4; k++) acc[k] = fmaf(w, (float)p[k], acc[k]);
        }
    }
#pragma unroll
    for (int off = 32; off > 0; off >>= 1) sv += __shfl_xor(sv, off);
#pragma unroll
    for (int k = 0; k < 4; k++) {
        acc[k] += __shfl_xor(acc[k], 16);
        acc[k] += __shfl_xor(acc[k], 32);
    }
    if (quarter == 0) {
        float wself = __expf(leaky02(a_s[i] + adi));
        float s = sv + wself;
        f16x4 ph = *((const f16x4*)(h + ((long)i << 6) + fq * 4));
        float4 gb = ((const float4*)gat_b)[fq];
        float4 cw = ((const float4*)cheb_w)[fq];
        float gbv[4] = {gb.x, gb.y, gb.z, gb.w};
        float cwv[4] = {cw.x, cw.y, cw.z, cw.w};
        float inv = 1.f / s;
        float z = 0.f;
#pragma unroll
        for (int k = 0; k < 4; k++) {
            float o = fmaxf(fmaf(wself, (float)ph[k], acc[k]) * inv + gbv[k], 0.f);
            z = fmaf(o, cwv[k], z);
        }
#pragma unroll
        for (int off = 8; off > 0; off >>= 1) z += __shfl_xor(z, off);
        if (fq == 0) out[i] = 1.f / (1.f + __expf(-(z + cheb_b[0])));
    }
}

extern "C" void kernel_launch(void* const* d_in, const int* in_sizes, int n_in,
                              void* d_out, int out_size, void* d_ws, size_t ws_size,
                              hipStream_t stream) {
    const float* x       = (const float*)d_in[0];
    const int*   eidx    = (const int*)d_in[1];
    const float* fb_w1   = (const float*)d_in[2];
    const float* fb_w2   = (const float*)d_in[3];
    const float* sage_wl = (const float*)d_in[4];
    const float* sage_bl = (const float*)d_in[5];
    const float* sage_wr = (const float*)d_in[6];
    const float* gat_w   = (const float*)d_in[7];
    const float* att_src = (const float*)d_in[8];
    const float* att_dst = (const float*)d_in[9];
    const float* gat_b   = (const float*)d_in[10];
    const float* cheb_w  = (const float*)d_in[11];
    const float* cheb_b  = (const float*)d_in[12];

    const int* src = eidx;
    const int* dst = eidx + N_EDGES;

    // workspace (~116 MB with aliasing)
    char* base = (char*)d_ws;
    f16* Xp = (f16*)base;                               //  0    .. 38.4 MB
    f16* H  = (f16*)(base + 38400000);                  // 38.4  .. 57.6 MB
    f16* Y  = (f16*)(base + 57600000);                  // 57.6  .. 96.0 MB
    f16* t_l = (f16*)base;                              // aliases Xp (dead after y)
    f16* x2  = (f16*)(base + 25600000);                 // aliases Xp-tail+H
    f16* h   = Y;                                       // aliases Y (dead after sage_lin)
    float* a_s = (float*)(base + 70400000);
    float* a_d = a_s + N_NODES;
    int* rowptr  = (int*)(base + 96000000);             // 100,001
    int* arrived = rowptr + (N_NODES + 1);              // 1
    int* cnt8    = arrived + 1;                         // 800,000 (8 replicas)
    int* roff8   = cnt8 + 8 * N_NODES;                  // 800,000
    int* esrc    = roff8 + 8 * N_NODES;                 // 1,600,000
    int* rank    = esrc + N_EDGES;                      // 1,600,000
    int* bsum    = rank + N_EDGES;                      // 98
    int* boff    = bsum + 128;                          // 98

    hipMemsetAsync(arrived, 0, (1 + 8 * N_NODES) * sizeof(int), stream);  // arrived+cnt8

    rank_xpad_kernel<<<25000, 256, 0, stream>>>(x, Xp, dst, cnt8, rank);
    scan_kernel<<<98, 1024, 0, stream>>>(cnt8, roff8, rowptr, bsum, boff, arrived);
    h_fill_kernel<<<384, 256, 0, stream>>>(Xp, fb_w1, H, src, dst, rank, rowptr, boff,
                                           roff8, esrc);
    y_kernel<<<768, 256, 0, stream>>>(Xp, H, fb_w2, Y);
    sage_lin_kernel<<<768, 256, 0, stream>>>(Y, sage_wl, sage_wr, sage_bl, t_l, x2);
    sage_agg_kernel<<<N_NODES / 4, 256, 0, stream>>>(t_l, rowptr, boff, esrc, x2);
    gat_h_kernel<<<392, 256, 0, stream>>>(x2, gat_w, att_src, att_dst, h, a_s, a_d);
    gat_agg_kernel<<<N_NODES / 4, 256, 0, stream>>>(h, a_s, a_d, rowptr, boff, esrc, gat_b,
                                                    cheb_w, cheb_b, (float*)d_out);
}